// Round 6
// baseline (1145.793 us; speedup 1.0000x reference)
//
#include <hip/hip_runtime.h>
#include <stdint.h>

// ---------------------------------------------------------------------------
// QUIK quantized linear, M=N=K=4096.
//   out[b,o] = (dot(x_q[b,:], w_q[o,:]) + bias[o]) * sa * sw
//              + (xmin + 4*sa) * wsum[b]            (B == out quirk: row index)
// Round 10: split-K 8-wave. Round 9 proved 4x4 wave tile (0.5 reads/MFMA)
// balances the LDS pipe (~2560 cy/iter/CU) with the matrix pipe (2342 cy),
// but at 4 waves / 1 per SIMD everything was latency-exposed (6375 cy/iter,
// MfmaUtil 32%). Now: 8 waves (512 thr), waves 0-3 accumulate K in [0,2048),
// waves 4-7 in [2048,4096), each wave a 128x128 tile (4x4 of 32x32). 2
// waves/SIMD restores latency hiding at the SAME pipe balance. Exact int32
// merge of the two K-halves through LDS at the end (values < 2^24 -> fp32
// reference accumulation is exact integer arithmetic; split-sum identical).
// ---------------------------------------------------------------------------

using i32x4  = __attribute__((ext_vector_type(4))) int;
using i32x16 = __attribute__((ext_vector_type(16))) int;

#define TID ((int)threadIdx.x)

// ---------------- stats: 8192 blocks, 16 KB each, no atomics ---------------
__global__ __launch_bounds__(256) void k_stats(const float4* __restrict__ x,
                                               const float4* __restrict__ w,
                                               float* __restrict__ pmin,
                                               float* __restrict__ pmax,
                                               float* __restrict__ wsum) {
  const int blk = blockIdx.x;
  const bool isw = blk < 4096;
  const float4* src = isw ? (w + (size_t)blk * 1024)
                          : (x + (size_t)(blk - 4096) * 1024);
  float4 v0 = src[TID], v1 = src[256 + TID], v2 = src[512 + TID], v3 = src[768 + TID];
  float lmin = fminf(fminf(fminf(v0.x, v0.y), fminf(v0.z, v0.w)),
                     fminf(fminf(v1.x, v1.y), fminf(v1.z, v1.w)));
  lmin = fminf(lmin, fminf(fminf(fminf(v2.x, v2.y), fminf(v2.z, v2.w)),
                           fminf(fminf(v3.x, v3.y), fminf(v3.z, v3.w))));
  float lmax = fmaxf(fmaxf(fmaxf(v0.x, v0.y), fmaxf(v0.z, v0.w)),
                     fmaxf(fmaxf(v1.x, v1.y), fmaxf(v1.z, v1.w)));
  lmax = fmaxf(lmax, fmaxf(fmaxf(fmaxf(v2.x, v2.y), fmaxf(v2.z, v2.w)),
                           fmaxf(fmaxf(v3.x, v3.y), fmaxf(v3.z, v3.w))));
  float lsum = ((v0.x + v0.y) + (v0.z + v0.w)) + ((v1.x + v1.y) + (v1.z + v1.w)) +
               ((v2.x + v2.y) + (v2.z + v2.w)) + ((v3.x + v3.y) + (v3.z + v3.w));

#pragma unroll
  for (int d = 32; d > 0; d >>= 1) {
    lmin = fminf(lmin, __shfl_down(lmin, d));
    lmax = fmaxf(lmax, __shfl_down(lmax, d));
    lsum += __shfl_down(lsum, d);
  }
  __shared__ float smn[4], smx[4], ssm[4];
  const int wv = TID >> 6;
  if ((TID & 63) == 0) { smn[wv] = lmin; smx[wv] = lmax; ssm[wv] = lsum; }
  __syncthreads();
  if (TID == 0) {
    float mn = fminf(fminf(smn[0], smn[1]), fminf(smn[2], smn[3]));
    float mx = fmaxf(fmaxf(smx[0], smx[1]), fmaxf(smx[2], smx[3]));
    pmin[blk] = mn; pmax[blk] = mx;
    if (isw) wsum[blk] = (ssm[0] + ssm[1]) + (ssm[2] + ssm[3]);
  }
}

// Single block: reduce 8192 partials -> mmf = {xmin, xmax, wmin, wmax}.
__global__ __launch_bounds__(256) void k_final(const float* __restrict__ pmin,
                                               const float* __restrict__ pmax,
                                               float* __restrict__ mmf) {
  float wmn = 1e30f, wmx = -1e30f, xmn = 1e30f, xmx = -1e30f;
  for (int i = TID; i < 4096; i += 256) {
    wmn = fminf(wmn, pmin[i]);        wmx = fmaxf(wmx, pmax[i]);
    xmn = fminf(xmn, pmin[4096 + i]); xmx = fmaxf(xmx, pmax[4096 + i]);
  }
#pragma unroll
  for (int d = 32; d > 0; d >>= 1) {
    xmn = fminf(xmn, __shfl_down(xmn, d));
    xmx = fmaxf(xmx, __shfl_down(xmx, d));
    wmn = fminf(wmn, __shfl_down(wmn, d));
    wmx = fmaxf(wmx, __shfl_down(wmx, d));
  }
  __shared__ float s[4][4];
  const int wv = TID >> 6;
  if ((TID & 63) == 0) { s[wv][0] = xmn; s[wv][1] = xmx; s[wv][2] = wmn; s[wv][3] = wmx; }
  __syncthreads();
  if (TID == 0) {
    mmf[0] = fminf(fminf(s[0][0], s[1][0]), fminf(s[2][0], s[3][0]));
    mmf[1] = fmaxf(fmaxf(s[0][1], s[1][1]), fmaxf(s[2][1], s[3][1]));
    mmf[2] = fminf(fminf(s[0][2], s[1][2]), fminf(s[2][2], s[3][2]));
    mmf[3] = fmaxf(fmaxf(s[0][3], s[1][3]), fmaxf(s[2][3], s[3][3]));
  }
}

// ---------------- quant: bit-exact np fp32 op replication -> int8 ----------
__device__ __forceinline__ int q1i(float t, float zero, float scale) {
  float v = (t - zero) / scale - 4.0f;   // IEEE div, matches np
  v = fminf(3.0f, fmaxf(-4.0f, v));
  return (int)v;                         // trunc toward zero == astype(int32)
}

__device__ __forceinline__ unsigned pack4(float4 v, float zero, float scale) {
  return (q1i(v.x, zero, scale) & 255) | ((q1i(v.y, zero, scale) & 255) << 8) |
         ((q1i(v.z, zero, scale) & 255) << 16) | ((q1i(v.w, zero, scale) & 255) << 24);
}

__global__ __launch_bounds__(256) void k_quant(const float4* __restrict__ x,
                                               const float4* __restrict__ w,
                                               uint4* __restrict__ Xq,
                                               uint4* __restrict__ Wq,
                                               const float* __restrict__ mmf) {
  bool isx = (blockIdx.x < 4096);
  int row = isx ? blockIdx.x : (blockIdx.x - 4096);
  const float4* in = (isx ? x : w) + (size_t)row * 1024 + TID * 4;
  uint4* outq = (isx ? Xq : Wq) + (size_t)row * 256 + TID;
  float zero = isx ? mmf[0] : mmf[2];
  float scale = ((isx ? mmf[1] : mmf[3]) - zero) * 0.125f;  // (max-min)/8 exact
  float4 a = in[0], b = in[1], c = in[2], d = in[3];
  uint4 o;
  o.x = pack4(a, zero, scale);
  o.y = pack4(b, zero, scale);
  o.z = pack4(c, zero, scale);
  o.w = pack4(d, zero, scale);
  *outq = o;
}

__device__ __forceinline__ void gload_lds16(const char* g, char* l) {
  __builtin_amdgcn_global_load_lds(
      (__attribute__((address_space(1))) void*)(g),
      (__attribute__((address_space(3))) void*)(l), 16, 0, 0);
}

// ---------------- GEMM: 256x256 block, 8 waves, in-block split-K ----------
// Wave w: K-half hh=w>>2 (hh*2048 base), quadrant wm=((w>>1)&1)*128,
// wn=(w&1)*128; 4x4 of mfma_i32_32x32x32_i8 (0.5 ds_reads/MFMA).
// LDS (128 KB): side s (dbuf), half hf: A at [s*65536 + hf*32768 + row*64 +
// pc*16], B same + 16384. Swizzle: physical chunk pc of row r holds logical
// chunk pc ^ ((r>>1)&3) (pre-swizzled global src, linear LDS dest). Bank-
// group of a 16-B slot = 4*(r&1) + pc -> c5->group bijective over c5&7.
// A-frag (HW-verified r3): lane holds A[row=wm+i*32+(lane&31)][k=kt*32+(lane>>5)*16+j].
// C/D (verified m74/m101): col = lane&31, row = (reg&3)+8*(reg>>2)+4*(lane>>5).
//
// Per iteration (K=64 per half, 32 iterations):
//   stage 8 gloads/thread (both halves' next slices -> side nxt), FIRST
//   each wave: 16 ds_read_b128 + 32 MFMA from its half's cur side
//   __syncthreads()
// Then: exact int32 merge (waves 4-7 -> LDS, waves 0-3 add), 2 rounds of
// 128 KB; epilogue by waves 0-3.
__global__ __launch_bounds__(512, 2) void k_gemm(const char* __restrict__ Xq,
                                                 const char* __restrict__ Wq,
                                                 const float* __restrict__ bias,
                                                 const float* __restrict__ wsum,
                                                 const float* __restrict__ mmf,
                                                 float* __restrict__ out) {
  __shared__ __align__(16) char LDS[131072];

  const int tid = TID;
  const int lane = tid & 63, wave = tid >> 6;
  const int c5 = lane & 31, hl = lane >> 5;
  const int hh = wave >> 2;                       // K-half
  const int wm = ((wave >> 1) & 1) * 128, wn = (wave & 1) * 128;

  // Bijective XCD swizzle: 256 blocks = 8 XCDs x 32 contiguous.
  const int bid = (int)blockIdx.x;
  const int swz = (bid & 7) * 32 + (bid >> 3);
  const int bx = swz & 15, by = swz >> 4;
  const int brow = by * 256, bcol = bx * 256;

  // Staging (512 threads): thread t -> row t>>2 (0..127) + g*128 of a
  // 256-row slice, physical chunk t&3, logical chunk (t&3)^((t>>3)&3)
  // [row bits 1-2 = tid bits 3-4; +128 rows vanishes mod 4 after >>1].
  // LDS dest = slice_base + g*8192 + t*16 (linear).
  const int srow = tid >> 2;
  const int lcg = (tid & 3) ^ ((tid >> 3) & 3);
  const char* gA = Xq + (size_t)(brow + srow) * 4096 + lcg * 16;
  const char* gB = Wq + (size_t)(bcol + srow) * 4096 + lcg * 16;

  // Read-side physical chunk for logical chunk (kt*2+hl): XOR with
  // (row>>1)&3; fragment rows are c5 + multiple-of-32 -> == (c5>>1)&3.
  const int rsw = (c5 >> 1) & 3;

  i32x16 acc[4][4];
#pragma unroll
  for (int i = 0; i < 4; ++i)
#pragma unroll
    for (int j = 0; j < 4; ++j)
#pragma unroll
      for (int e = 0; e < 16; ++e) acc[i][j][e] = 0;

  // Prologue: stage iteration-0 slices of both halves into side 0.
#pragma unroll
  for (int hf = 0; hf < 2; ++hf) {
    const char* gAh = gA + hf * 2048;
    const char* gBh = gB + hf * 2048;
    char* dA = LDS + hf * 32768 + tid * 16;
    char* dB = dA + 16384;
#pragma unroll
    for (int g = 0; g < 2; ++g) {
      gload_lds16(gAh + (size_t)g * (128 * 4096), dA + g * 8192);
      gload_lds16(gBh + (size_t)g * (128 * 4096), dB + g * 8192);
    }
  }
  __syncthreads();

#pragma unroll 2
  for (int it = 0; it < 31; ++it) {
    const int cur = it & 1, nxt = cur ^ 1;
    const size_t kOff = (size_t)(it + 1) * 64;  // K-slice being staged

    // Stage both halves' next slices (8 gloads -> side nxt), issued first.
#pragma unroll
    for (int hf = 0; hf < 2; ++hf) {
      const char* gAh = gA + hf * 2048 + kOff;
      const char* gBh = gB + hf * 2048 + kOff;
      char* dA = LDS + nxt * 65536 + hf * 32768 + tid * 16;
      char* dB = dA + 16384;
#pragma unroll
      for (int g = 0; g < 2; ++g) {
        gload_lds16(gAh + (size_t)g * (128 * 4096), dA + g * 8192);
        gload_lds16(gBh + (size_t)g * (128 * 4096), dB + g * 8192);
      }
    }

    // Compute this wave's half: 16 ds_reads + 32 MFMAs, free-flow.
    {
      const int hbase = cur * 65536 + hh * 32768;
#pragma unroll
      for (int kt = 0; kt < 2; ++kt) {
        const int pco = ((kt * 2 + hl) ^ rsw) * 16;
        const int ab = hbase + pco;
        const int bb = hbase + 16384 + pco;
        i32x4 af0 = *(const i32x4*)(LDS + ab + (wm + c5) * 64);
        i32x4 af1 = *(const i32x4*)(LDS + ab + (wm + 32 + c5) * 64);
        i32x4 af2 = *(const i32x4*)(LDS + ab + (wm + 64 + c5) * 64);
        i32x4 af3 = *(const i32x4*)(LDS + ab + (wm + 96 + c5) * 64);
        i32x4 bf0 = *(const i32x4*)(LDS + bb + (wn + c5) * 64);
        i32x4 bf1 = *(const i32x4*)(LDS + bb + (wn + 32 + c5) * 64);
        i32x4 bf2 = *(const i32x4*)(LDS + bb + (wn + 64 + c5) * 64);
        i32x4 bf3 = *(const i32x4*)(LDS + bb + (wn + 96 + c5) * 64);
#pragma unroll
        for (int i = 0; i < 4; ++i) {
          const i32x4 af = (i == 0) ? af0 : (i == 1) ? af1 : (i == 2) ? af2 : af3;
          acc[i][0] = __builtin_amdgcn_mfma_i32_32x32x32_i8(af, bf0, acc[i][0], 0, 0, 0);
          acc[i][1] = __builtin_amdgcn_mfma_i32_32x32x32_i8(af, bf1, acc[i][1], 0, 0, 0);
          acc[i][2] = __builtin_amdgcn_mfma_i32_32x32x32_i8(af, bf2, acc[i][2], 0, 0, 0);
          acc[i][3] = __builtin_amdgcn_mfma_i32_32x32x32_i8(af, bf3, acc[i][3], 0, 0, 0);
        }
      }
    }

    // One sync point per iteration: drains this iter's staging loads (a full
    // compute region between issue and consumption) + WAR/RAW barrier.
    __syncthreads();
  }

  // Tail: iteration 31 from side 1 (landed at it=30's barrier).
  {
    const int hbase = 65536 + hh * 32768;
#pragma unroll
    for (int kt = 0; kt < 2; ++kt) {
      const int pco = ((kt * 2 + hl) ^ rsw) * 16;
      const int ab = hbase + pco;
      const int bb = hbase + 16384 + pco;
      i32x4 af0 = *(const i32x4*)(LDS + ab + (wm + c5) * 64);
      i32x4 af1 = *(const i32x4*)(LDS + ab + (wm + 32 + c5) * 64);
      i32x4 af2 = *(const i32x4*)(LDS + ab + (wm + 64 + c5) * 64);
      i32x4 af3 = *(const i32x4*)(LDS + ab + (wm + 96 + c5) * 64);
      i32x4 bf0 = *(const i32x4*)(LDS + bb + (wn + c5) * 64);
      i32x4 bf1 = *(const i32x4*)(LDS + bb + (wn + 32 + c5) * 64);
      i32x4 bf2 = *(const i32x4*)(LDS + bb + (wn + 64 + c5) * 64);
      i32x4 bf3 = *(const i32x4*)(LDS + bb + (wn + 96 + c5) * 64);
#pragma unroll
      for (int i = 0; i < 4; ++i) {
        const i32x4 af = (i == 0) ? af0 : (i == 1) ? af1 : (i == 2) ? af2 : af3;
        acc[i][0] = __builtin_amdgcn_mfma_i32_32x32x32_i8(af, bf0, acc[i][0], 0, 0, 0);
        acc[i][1] = __builtin_amdgcn_mfma_i32_32x32x32_i8(af, bf1, acc[i][1], 0, 0, 0);
        acc[i][2] = __builtin_amdgcn_mfma_i32_32x32x32_i8(af, bf2, acc[i][2], 0, 0, 0);
        acc[i][3] = __builtin_amdgcn_mfma_i32_32x32x32_i8(af, bf3, acc[i][3], 0, 0, 0);
      }
    }
  }

  // Merge K-halves (exact int32): waves 4-7 write, paired waves 0-3 add.
  // 2 rounds x 128 KB; chunk c of lane l at (wave&3)*32768 + c*1024 + l*16
  // (lanes stride 16 B -> full bank spread).
#pragma unroll
  for (int r = 0; r < 2; ++r) {
    __syncthreads();
    if (wave >= 4) {
      char* mb = LDS + (wave & 3) * 32768 + lane * 16;
#pragma unroll
      for (int i = 0; i < 2; ++i)
#pragma unroll
        for (int j = 0; j < 4; ++j) {
          i32x16 v = acc[2 * r + i][j];
#pragma unroll
          for (int q = 0; q < 4; ++q) {
            i32x4 p = {v[4 * q], v[4 * q + 1], v[4 * q + 2], v[4 * q + 3]};
            *(i32x4*)(mb + ((i * 4 + j) * 4 + q) * 1024) = p;
          }
        }
    }
    __syncthreads();
    if (wave < 4) {
      const char* mb = LDS + wave * 32768 + lane * 16;
#pragma unroll
      for (int i = 0; i < 2; ++i)
#pragma unroll
        for (int j = 0; j < 4; ++j)
#pragma unroll
          for (int q = 0; q < 4; ++q) {
            i32x4 p = *(const i32x4*)(mb + ((i * 4 + j) * 4 + q) * 1024);
            acc[2 * r + i][j][4 * q + 0] += p[0];
            acc[2 * r + i][j][4 * q + 1] += p[1];
            acc[2 * r + i][j][4 * q + 2] += p[2];
            acc[2 * r + i][j][4 * q + 3] += p[3];
          }
    }
  }

  // Epilogue (ref op order preserved bit-exactly), waves 0-3 only.
  if (wave < 4) {
    float sa = (mmf[1] - mmf[0]) * 0.125f;
    float sw = (mmf[3] - mmf[2]) * 0.125f;
    float mid = mmf[0] + 4.0f * sa;

    const int col0 = bcol + wn + c5;
    const float b0 = bias[col0],      b1 = bias[col0 + 32];
    const float b2 = bias[col0 + 64], b3 = bias[col0 + 96];
#pragma unroll
    for (int i = 0; i < 4; ++i) {
      const int rbase = brow + wm + i * 32 + 4 * hl;
#pragma unroll
      for (int g = 0; g < 4; ++g) {
#pragma unroll
        for (int q = 0; q < 4; ++q) {
          const int row = rbase + 8 * g + q;
          const float shift = mid * wsum[row];
          float* po = out + (size_t)row * 4096 + col0;
          po[0]  = ((float)acc[i][0][g * 4 + q] + b0) * sa * sw + shift;
          po[32] = ((float)acc[i][1][g * 4 + q] + b1) * sa * sw + shift;
          po[64] = ((float)acc[i][2][g * 4 + q] + b2) * sa * sw + shift;
          po[96] = ((float)acc[i][3][g * 4 + q] + b3) * sa * sw + shift;
        }
      }
    }
  }
}

extern "C" void kernel_launch(void* const* d_in, const int* in_sizes, int n_in,
                              void* d_out, int out_size, void* d_ws, size_t ws_size,
                              hipStream_t stream) {
  (void)in_sizes; (void)n_in; (void)out_size; (void)ws_size;
  const float* x = (const float*)d_in[0];
  const float* w = (const float*)d_in[1];
  const float* bias = (const float*)d_in[2];
  float* out = (float*)d_out;

  char* ws = (char*)d_ws;
  float* mmf = (float*)ws;                             // 4 floats: xmin,xmax,wmin,wmax
  float* wsum = (float*)(ws + 1024);                   // 4096 floats
  float* pmin = (float*)(ws + 32768);                  // 8192 floats
  float* pmax = (float*)(ws + 65536);                  // 8192 floats
  char* Xq = ws + 131072;                              // 4096x4096 i8 (16.8 MB)
  char* Wq = ws + 131072 + (size_t)16777216;           // 4096x4096 i8 (16.8 MB)

  k_stats<<<8192, 256, 0, stream>>>((const float4*)x, (const float4*)w, pmin, pmax, wsum);
  k_final<<<1, 256, 0, stream>>>(pmin, pmax, mmf);
  k_quant<<<8192, 256, 0, stream>>>((const float4*)x, (const float4*)w,
                                    (uint4*)Xq, (uint4*)Wq, mmf);
  k_gemm<<<256, 512, 0, stream>>>(Xq, Wq, bias, wsum, mmf, out);
}

// Round 7
// 246.465 us; speedup vs baseline: 4.6489x; 4.6489x over previous
//
#include <hip/hip_runtime.h>
#include <stdint.h>

// ---------------------------------------------------------------------------
// QUIK quantized linear, M=N=K=4096.
//   out[b,o] = (dot(x_q[b,:], w_q[o,:]) + bias[o]) * sa * sw
//              + (xmin + 4*sa) * wsum[b]            (B == out quirk: row index)
// Round 11: GEMM reverted verbatim to round-7 free-flow halves (best: ~69.5
// us; round-10 split-K proved 4x4 acc (256 VGPR) + 2 waves/SIMD impossible --
// spill -> 4.8 GB scratch traffic). This round attacks the constant ~175 us
// non-GEMM residual (ideal ~50): stats/quant restructured from 8192 tiny
// blocks (64 B/thread) to 2048 blocks with 4x work per thread.
// ---------------------------------------------------------------------------

using i32x4  = __attribute__((ext_vector_type(4))) int;
using i32x16 = __attribute__((ext_vector_type(16))) int;

#define TID ((int)threadIdx.x)

// ---------------- stats: 2048 blocks, 1 wave per row, 256 B/thread ---------
// Rows 0..4095 = w, 4096..8191 = x (block b -> rows 4b..4b+3, wave = row).
__global__ __launch_bounds__(256) void k_stats(const float4* __restrict__ x,
                                               const float4* __restrict__ w,
                                               float* __restrict__ pmin,
                                               float* __restrict__ pmax,
                                               float* __restrict__ wsum) {
  const int blk = blockIdx.x;
  const int wv = TID >> 6, ll = TID & 63;
  const int row = blk * 4 + wv;
  const bool isw = row < 4096;
  const float4* src = (isw ? w + (size_t)row * 1024
                           : x + (size_t)(row - 4096) * 1024) + ll;
  float lmin = 1e30f, lmax = -1e30f, lsum = 0.0f;
#pragma unroll
  for (int i = 0; i < 16; ++i) {
    float4 v = src[i * 64];
    lmin = fminf(lmin, fminf(fminf(v.x, v.y), fminf(v.z, v.w)));
    lmax = fmaxf(lmax, fmaxf(fmaxf(v.x, v.y), fmaxf(v.z, v.w)));
    lsum += (v.x + v.y) + (v.z + v.w);
  }
#pragma unroll
  for (int d = 32; d > 0; d >>= 1) {
    lmin = fminf(lmin, __shfl_down(lmin, d));
    lmax = fmaxf(lmax, __shfl_down(lmax, d));
    lsum += __shfl_down(lsum, d);
  }
  __shared__ float smn[4], smx[4];
  if (ll == 0) {
    if (isw) wsum[row] = lsum;
    smn[wv] = lmin; smx[wv] = lmax;
  }
  __syncthreads();
  if (TID == 0) {
    pmin[blk] = fminf(fminf(smn[0], smn[1]), fminf(smn[2], smn[3]));
    pmax[blk] = fmaxf(fmaxf(smx[0], smx[1]), fmaxf(smx[2], smx[3]));
  }
}

// Single block: reduce 2048 partials -> mmf = {xmin, xmax, wmin, wmax}.
// Blocks 0..1023 were pure-w, 1024..2047 pure-x.
__global__ __launch_bounds__(256) void k_final(const float* __restrict__ pmin,
                                               const float* __restrict__ pmax,
                                               float* __restrict__ mmf) {
  float wmn = 1e30f, wmx = -1e30f, xmn = 1e30f, xmx = -1e30f;
  for (int i = TID; i < 1024; i += 256) {
    wmn = fminf(wmn, pmin[i]);        wmx = fmaxf(wmx, pmax[i]);
    xmn = fminf(xmn, pmin[1024 + i]); xmx = fmaxf(xmx, pmax[1024 + i]);
  }
#pragma unroll
  for (int d = 32; d > 0; d >>= 1) {
    xmn = fminf(xmn, __shfl_down(xmn, d));
    xmx = fmaxf(xmx, __shfl_down(xmx, d));
    wmn = fminf(wmn, __shfl_down(wmn, d));
    wmx = fmaxf(wmx, __shfl_down(wmx, d));
  }
  __shared__ float s[4][4];
  const int wv = TID >> 6;
  if ((TID & 63) == 0) { s[wv][0] = xmn; s[wv][1] = xmx; s[wv][2] = wmn; s[wv][3] = wmx; }
  __syncthreads();
  if (TID == 0) {
    mmf[0] = fminf(fminf(s[0][0], s[1][0]), fminf(s[2][0], s[3][0]));
    mmf[1] = fmaxf(fmaxf(s[0][1], s[1][1]), fmaxf(s[2][1], s[3][1]));
    mmf[2] = fminf(fminf(s[0][2], s[1][2]), fminf(s[2][2], s[3][2]));
    mmf[3] = fmaxf(fmaxf(s[0][3], s[1][3]), fmaxf(s[2][3], s[3][3]));
  }
}

// ---------------- quant: bit-exact np fp32 op replication -> int8 ----------
__device__ __forceinline__ int q1i(float t, float zero, float scale) {
  float v = (t - zero) / scale - 4.0f;   // IEEE div, matches np
  v = fminf(3.0f, fmaxf(-4.0f, v));
  return (int)v;                         // trunc toward zero == astype(int32)
}

__device__ __forceinline__ unsigned pack4(float4 v, float zero, float scale) {
  return (q1i(v.x, zero, scale) & 255) | ((q1i(v.y, zero, scale) & 255) << 8) |
         ((q1i(v.z, zero, scale) & 255) << 16) | ((q1i(v.w, zero, scale) & 255) << 24);
}

// 2048 blocks x 4-row loop (row body identical to the proven version).
__global__ __launch_bounds__(256) void k_quant(const float4* __restrict__ x,
                                               const float4* __restrict__ w,
                                               uint4* __restrict__ Xq,
                                               uint4* __restrict__ Wq,
                                               const float* __restrict__ mmf) {
  const int blk = blockIdx.x;
#pragma unroll
  for (int rr = 0; rr < 4; ++rr) {
    const int rowid = blk * 4 + rr;
    const bool isx = rowid < 4096;
    const int row = isx ? rowid : (rowid - 4096);
    const float4* in = (isx ? x : w) + (size_t)row * 1024 + TID * 4;
    uint4* outq = (isx ? Xq : Wq) + (size_t)row * 256 + TID;
    const float zero = isx ? mmf[0] : mmf[2];
    const float scale = ((isx ? mmf[1] : mmf[3]) - zero) * 0.125f;  // exact /8
    float4 a = in[0], b = in[1], c = in[2], d = in[3];
    uint4 o;
    o.x = pack4(a, zero, scale);
    o.y = pack4(b, zero, scale);
    o.z = pack4(c, zero, scale);
    o.w = pack4(d, zero, scale);
    *outq = o;
  }
}

__device__ __forceinline__ void gload_lds16(const char* g, char* l) {
  __builtin_amdgcn_global_load_lds(
      (__attribute__((address_space(1))) void*)(g),
      (__attribute__((address_space(3))) void*)(l), 16, 0, 0);
}

// ---------------- GEMM: block 256x256, 8 waves, free-flow halves ----------
// (Round-7 kernel, verbatim: best measured ~69.5 us.)
// LDS map (128 KB): A at [side*32768 + kk*16384 + row*64 + pc*16], side=dbuf,
// kk = K-subtile (BK=64) within iteration; B same + 65536.
// Swizzle: physical chunk pc of row r holds logical chunk pc ^ ((r>>1)&3)
// (pre-swizzled global src, linear LDS dest -- required by global_load_lds).
// Wave w: rows wm=(w>>2)*128, cols wn=(w&3)*64; 4x2 of mfma_i32_32x32x32_i8.
// A-frag (HW-verified r3): lane holds A[row=wm+i*32+(lane&31)][k=kt*32+(lane>>5)*16+j].
// C/D (verified m74/m101): col = lane&31, row = (reg&3)+8*(reg>>2)+4*(lane>>5).
//
// Schedule per iteration (2 BK=64 sub-tiles), 2 free-flow halves:
//   half kk: stage 4x global_load_lds (next iter's kk slice -> nxt),
//            12 ds_read_b128 (cur, kk), 16 MFMA -- compiler-scheduled
//   s_waitcnt vmcnt(4) ; s_barrier   (previous half's 4 loads drained;
//                                     this half's 4 stay in flight)
__global__ __launch_bounds__(512, 2) void k_gemm(const char* __restrict__ Xq,
                                                 const char* __restrict__ Wq,
                                                 const float* __restrict__ bias,
                                                 const float* __restrict__ wsum,
                                                 const float* __restrict__ mmf,
                                                 float* __restrict__ out) {
  __shared__ __align__(16) char LDS[131072];

  const int tid = TID;
  const int lane = tid & 63, wave = tid >> 6;
  const int c5 = lane & 31, h = lane >> 5;
  const int wm = (wave >> 2) * 128, wn = (wave & 3) * 64;

  // Bijective XCD swizzle: 256 blocks = 8 XCDs x 32 contiguous.
  const int bid = (int)blockIdx.x;
  const int swz = (bid & 7) * 32 + (bid >> 3);
  const int bx = swz & 15, by = swz >> 4;
  const int brow = by * 256, bcol = bx * 256;

  // Staging: thread t -> row t>>2 of a 128-row slice, physical chunk t&3,
  // logical chunk (t&3)^((t>>3)&3). LDS dest = slice_base + t*16 (linear).
  const int srow = tid >> 2;
  const int lcg = (tid & 3) ^ ((tid >> 3) & 3);
  const char* gA = Xq + (size_t)(brow + srow) * 4096 + lcg * 16;
  const char* gB = Wq + (size_t)(bcol + srow) * 4096 + lcg * 16;

  // Read-side physical chunk for logical chunk (kt*2+h): XOR with (row>>1)&3;
  // all fragment rows are c5 + multiple-of-64 -> (row>>1)&3 == (c5>>1)&3.
  const int rsw = (c5 >> 1) & 3;

  i32x16 acc[4][2];
#pragma unroll
  for (int i = 0; i < 4; ++i)
#pragma unroll
    for (int j = 0; j < 2; ++j)
#pragma unroll
      for (int e = 0; e < 16; ++e) acc[i][j][e] = 0;

  // Prologue: stage tile-pair 0 into side 0. Issue order matches the loop's
  // half order: [A0,A0,B0,B0][A1,A1,B1,B1] so vmcnt counting lines up.
#pragma unroll
  for (int kk = 0; kk < 2; ++kk) {
    char* ldA = LDS + kk * 16384 + tid * 16;
    char* ldB = LDS + 65536 + kk * 16384 + tid * 16;
    gload_lds16(gA + (size_t)kk * 64, ldA);
    gload_lds16(gA + (size_t)kk * 64 + (size_t)(128 * 4096), ldA + 8192);
    gload_lds16(gB + (size_t)kk * 64, ldB);
    gload_lds16(gB + (size_t)kk * 64 + (size_t)(128 * 4096), ldB + 8192);
  }
  asm volatile("s_waitcnt vmcnt(4)" ::: "memory");  // kk0 slices landed
  __builtin_amdgcn_s_barrier();

#pragma unroll 2
  for (int it = 0; it < 31; ++it) {
    const int cur = it & 1, nxt = cur ^ 1;
    const int curA = cur * 32768, curB = 65536 + cur * 32768;
    const int nxtA = nxt * 32768, nxtB = 65536 + nxt * 32768;
    const size_t kOff = (size_t)(2 * it + 2) * 64;  // tile-pair being staged
#pragma unroll
    for (int kk = 0; kk < 2; ++kk) {
      // Stage this kk slice of the next tile-pair (4 loads -> side nxt).
      char* ldA = LDS + nxtA + kk * 16384 + tid * 16;
      char* ldB = LDS + nxtB + kk * 16384 + tid * 16;
      gload_lds16(gA + kOff + (size_t)kk * 64, ldA);
      gload_lds16(gA + kOff + (size_t)kk * 64 + (size_t)(128 * 4096), ldA + 8192);
      gload_lds16(gB + kOff + (size_t)kk * 64, ldB);
      gload_lds16(gB + kOff + (size_t)kk * 64 + (size_t)(128 * 4096), ldB + 8192);

      // Compute this kk sub-tile: 12 ds_reads + 16 MFMAs, free-flow
      // (compiler interleaves kt=1 reads under kt=0 MFMAs).
#pragma unroll
      for (int kt = 0; kt < 2; ++kt) {
        const int pco = ((kt * 2 + h) ^ rsw) * 16;
        const int ab = curA + kk * 16384 + pco;
        const int bb = curB + kk * 16384 + pco;
        i32x4 af0 = *(const i32x4*)(LDS + ab + (wm + c5) * 64);
        i32x4 af1 = *(const i32x4*)(LDS + ab + (wm + 32 + c5) * 64);
        i32x4 af2 = *(const i32x4*)(LDS + ab + (wm + 64 + c5) * 64);
        i32x4 af3 = *(const i32x4*)(LDS + ab + (wm + 96 + c5) * 64);
        i32x4 bf0 = *(const i32x4*)(LDS + bb + (wn + c5) * 64);
        i32x4 bf1 = *(const i32x4*)(LDS + bb + (wn + 32 + c5) * 64);
        acc[0][0] = __builtin_amdgcn_mfma_i32_32x32x32_i8(af0, bf0, acc[0][0], 0, 0, 0);
        acc[0][1] = __builtin_amdgcn_mfma_i32_32x32x32_i8(af0, bf1, acc[0][1], 0, 0, 0);
        acc[1][0] = __builtin_amdgcn_mfma_i32_32x32x32_i8(af1, bf0, acc[1][0], 0, 0, 0);
        acc[1][1] = __builtin_amdgcn_mfma_i32_32x32x32_i8(af1, bf1, acc[1][1], 0, 0, 0);
        acc[2][0] = __builtin_amdgcn_mfma_i32_32x32x32_i8(af2, bf0, acc[2][0], 0, 0, 0);
        acc[2][1] = __builtin_amdgcn_mfma_i32_32x32x32_i8(af2, bf1, acc[2][1], 0, 0, 0);
        acc[3][0] = __builtin_amdgcn_mfma_i32_32x32x32_i8(af3, bf0, acc[3][0], 0, 0, 0);
        acc[3][1] = __builtin_amdgcn_mfma_i32_32x32x32_i8(af3, bf1, acc[3][1], 0, 0, 0);
      }

      // Half boundary: drain the PREVIOUS half's 4 loads (next half's data),
      // keep this half's 4 in flight. Barrier globalizes residency + WAR.
      asm volatile("s_waitcnt vmcnt(4)" ::: "memory");
      __builtin_amdgcn_s_barrier();
    }
  }

  // Tail: tile-pair 62/63 in side 1. In flight at entry: 4 loads (side1 kk1).
#pragma unroll
  for (int kk = 0; kk < 2; ++kk) {
#pragma unroll
    for (int kt = 0; kt < 2; ++kt) {
      const int pco = ((kt * 2 + h) ^ rsw) * 16;
      const int ab = 32768 + kk * 16384 + pco;
      const int bb = 98304 + kk * 16384 + pco;
      i32x4 af0 = *(const i32x4*)(LDS + ab + (wm + c5) * 64);
      i32x4 af1 = *(const i32x4*)(LDS + ab + (wm + 32 + c5) * 64);
      i32x4 af2 = *(const i32x4*)(LDS + ab + (wm + 64 + c5) * 64);
      i32x4 af3 = *(const i32x4*)(LDS + ab + (wm + 96 + c5) * 64);
      i32x4 bf0 = *(const i32x4*)(LDS + bb + (wn + c5) * 64);
      i32x4 bf1 = *(const i32x4*)(LDS + bb + (wn + 32 + c5) * 64);
      acc[0][0] = __builtin_amdgcn_mfma_i32_32x32x32_i8(af0, bf0, acc[0][0], 0, 0, 0);
      acc[0][1] = __builtin_amdgcn_mfma_i32_32x32x32_i8(af0, bf1, acc[0][1], 0, 0, 0);
      acc[1][0] = __builtin_amdgcn_mfma_i32_32x32x32_i8(af1, bf0, acc[1][0], 0, 0, 0);
      acc[1][1] = __builtin_amdgcn_mfma_i32_32x32x32_i8(af1, bf1, acc[1][1], 0, 0, 0);
      acc[2][0] = __builtin_amdgcn_mfma_i32_32x32x32_i8(af2, bf0, acc[2][0], 0, 0, 0);
      acc[2][1] = __builtin_amdgcn_mfma_i32_32x32x32_i8(af2, bf1, acc[2][1], 0, 0, 0);
      acc[3][0] = __builtin_amdgcn_mfma_i32_32x32x32_i8(af3, bf0, acc[3][0], 0, 0, 0);
      acc[3][1] = __builtin_amdgcn_mfma_i32_32x32x32_i8(af3, bf1, acc[3][1], 0, 0, 0);
    }
    if (kk == 0) {
      // kk1 data is the 4 still-in-flight loads: drain before reading.
      asm volatile("s_waitcnt vmcnt(0)" ::: "memory");
      __builtin_amdgcn_s_barrier();
    }
  }

  // Epilogue (ref op order preserved bit-exactly).
  float sa = (mmf[1] - mmf[0]) * 0.125f;
  float sw = (mmf[3] - mmf[2]) * 0.125f;
  float mid = mmf[0] + 4.0f * sa;

  const int col0 = bcol + wn + c5;
  const float b0 = bias[col0], b1 = bias[col0 + 32];
#pragma unroll
  for (int i = 0; i < 4; ++i) {
    const int rbase = brow + wm + i * 32 + 4 * h;
#pragma unroll
    for (int g = 0; g < 4; ++g) {
#pragma unroll
      for (int q = 0; q < 4; ++q) {
        const int row = rbase + 8 * g + q;
        const float shift = mid * wsum[row];
        float* po = out + (size_t)row * 4096 + col0;
        po[0]  = ((float)acc[i][0][g * 4 + q] + b0) * sa * sw + shift;
        po[32] = ((float)acc[i][1][g * 4 + q] + b1) * sa * sw + shift;
      }
    }
  }
}

extern "C" void kernel_launch(void* const* d_in, const int* in_sizes, int n_in,
                              void* d_out, int out_size, void* d_ws, size_t ws_size,
                              hipStream_t stream) {
  (void)in_sizes; (void)n_in; (void)out_size; (void)ws_size;
  const float* x = (const float*)d_in[0];
  const float* w = (const float*)d_in[1];
  const float* bias = (const float*)d_in[2];
  float* out = (float*)d_out;

  char* ws = (char*)d_ws;
  float* mmf = (float*)ws;                             // 4 floats: xmin,xmax,wmin,wmax
  float* wsum = (float*)(ws + 1024);                   // 4096 floats
  float* pmin = (float*)(ws + 32768);                  // 2048 floats
  float* pmax = (float*)(ws + 65536);                  // 2048 floats
  char* Xq = ws + 131072;                              // 4096x4096 i8 (16.8 MB)
  char* Wq = ws + 131072 + (size_t)16777216;           // 4096x4096 i8 (16.8 MB)

  k_stats<<<2048, 256, 0, stream>>>((const float4*)x, (const float4*)w, pmin, pmax, wsum);
  k_final<<<1, 256, 0, stream>>>(pmin, pmax, mmf);
  k_quant<<<2048, 256, 0, stream>>>((const float4*)x, (const float4*)w,
                                    (uint4*)Xq, (uint4*)Wq, mmf);
  k_gemm<<<256, 512, 0, stream>>>(Xq, Wq, bias, wsum, mmf, out);
}